// Round 5
// baseline (113.445 us; speedup 1.0000x reference)
//
#include <hip/hip_runtime.h>
#include <math.h>

typedef __attribute__((ext_vector_type(8))) short bf16x8;
typedef __attribute__((ext_vector_type(4))) float f32x4;

#define W1S_OFF 0
#define W2S_OFF 262144
#define MZ_OFF  393216          // motifs_z, [p=m*64+c][16] bf16 (12 used, 4 pad)

__device__ __forceinline__ ushort f2bf(float x){
    union{float f; unsigned u;} v; v.f = x;
    unsigned r = v.u + 0x7fffu + ((v.u >> 16) & 1u);
    return (ushort)(r >> 16);
}
__device__ __forceinline__ float bf2f(ushort u){
    union{unsigned i; float f;} v; v.i = ((unsigned)u) << 16; return v.f;
}

// Pack W1 (512x512) and W2 (512x256) into bf16 MFMA-B-fragment order.
// B-frag layout: ws[((tn_g*16 + tk)*64 + lane)*8 + j] = W[k][n],
//   k = tk*32 + (lane>>4)*8 + j,  n = tn_g*16 + (lane&15).
__global__ __launch_bounds__(256) void prep_kernel(
    const float* __restrict__ W1, const float* __restrict__ W2,
    const float* __restrict__ motifs, ushort* __restrict__ ws)
{
    int idx = blockIdx.x * 256 + threadIdx.x;
    if (idx < 262144) {                        // W1: idx = k*512 + n
        int k = idx >> 9, n = idx & 511;
        int tk = k >> 5, j = k & 7, hig = (k >> 3) & 3;
        int tn = n >> 4, lo = n & 15;
        int lane = hig * 16 + lo;
        ws[W1S_OFF + (((tn*16 + tk)*64 + lane)*8 + j)] = f2bf(W1[idx]);
    } else if (idx < 393216) {                 // W2: i = k*256 + n
        int i = idx - 262144;
        int k = i >> 8, n = i & 255;
        int tk = k >> 5, j = k & 7, hig = (k >> 3) & 3;
        int tn = n >> 4, lo = n & 15;
        int lane = hig * 16 + lo;
        ws[W2S_OFF + (((tn*16 + tk)*64 + lane)*8 + j)] = f2bf(W2[i]);
    } else if (idx < 393216 + 512) {
        int p = idx - 393216;                  // p = m*64 + c
        const float* mp = motifs + p*12;
        float v[12]; float sm = 0.f;
        #pragma unroll
        for (int l = 0; l < 12; ++l){ v[l] = mp[l]; sm += v[l]; }
        float mean = sm * (1.f/12.f), sq = 0.f;
        #pragma unroll
        for (int l = 0; l < 12; ++l){ float d = v[l]-mean; sq = fmaf(d,d,sq); }
        float inv = 1.f / (sqrtf(sq*(1.f/12.f)) + 1e-8f);
        #pragma unroll
        for (int l = 0; l < 12; ++l) ws[MZ_OFF + p*16 + l] = f2bf((v[l]-mean)*inv);
        #pragma unroll
        for (int l = 12; l < 16; ++l) ws[MZ_OFF + p*16 + l] = 0;
    }
}

// Swizzled byte offset into the [64][512] bf16 LDS tile (conflict-free b128 A-frag reads)
#define SWZ(r, k) (((((r) << 9) + (k)) << 1) ^ (((r) & 7) << 4))

__global__ __launch_bounds__(512, 4) void fused_kernel(
    const float* __restrict__ x, const ushort* __restrict__ ws,
    const float* __restrict__ b1, const float* __restrict__ gamma,
    const float* __restrict__ beta, const float* __restrict__ b2,
    float* __restrict__ out)
{
    __shared__ __align__(16) ushort fl[64*512];   // 64 KB: flat -> hn -> fp32 out tile
    __shared__ float part[64][8][2];              // per-wave LN partials
    __shared__ float mu_s[64];
    __shared__ float rs_s[64];

    const int t  = threadIdx.x;
    const int g0 = blockIdx.x * 64;               // global row base (row = bi*4096+s)

    const int w    = t >> 6;          // wave 0..7
    const int lane = t & 63;
    const int hi   = lane >> 4;
    const int lo   = lane & 15;
    const int n0   = w * 64;

    // ---------------- Phase A: motif correlation -> flat (bf16, swizzled) ----------------
    {
        const int c  = t & 63;
        const int rg = t >> 6;                    // rows rg*8 .. rg*8+7
        const ushort* mzw = ws + MZ_OFF;
        const int sbase = (g0 & 4095) + rg*8;     // row-in-batch of this thread's first row
        const size_t xbase = (size_t)(g0 & ~4095) * 64 + c;

        for (int rq = 0; rq < 2; ++rq) {
            const int s0r = sbase + rq*4;         // row-in-batch for q=0
            float wv[12];
            #pragma unroll
            for (int l = 0; l < 12; ++l) {        // initial window (left-clamped)
                int sw = s0r - 11 + l; sw = sw < 0 ? 0 : sw;
                wv[l] = x[xbase + (size_t)sw * 64];
            }
            float wz[4][12];
            #pragma unroll
            for (int q = 0; q < 4; ++q) {
                if (q) {                          // slide window by one row
                    #pragma unroll
                    for (int l = 0; l < 11; ++l) wv[l] = wv[l+1];
                    wv[11] = x[xbase + (size_t)(s0r + q) * 64];
                }
                float sm = 0.f;
                #pragma unroll
                for (int l = 0; l < 12; ++l) sm += wv[l];
                float mean = sm * (1.f/12.f), sq = 0.f;
                #pragma unroll
                for (int l = 0; l < 12; ++l){ float d = wv[l]-mean; sq = fmaf(d,d,sq); }
                float inv = 1.f / (sqrtf(sq*(1.f/12.f)) + 1e-8f);
                #pragma unroll
                for (int l = 0; l < 12; ++l) wz[q][l] = (wv[l]-mean)*inv;
            }
            for (int m = 0; m < 8; ++m) {
                const uint4* mp4 = (const uint4*)(mzw + (m*64 + c)*16);
                uint4 u0 = mp4[0];
                uint2 u1 = *(const uint2*)(mzw + (m*64 + c)*16 + 8);
                float mzv[12];
                mzv[0] = bf2f((ushort)(u0.x & 0xffffu)); mzv[1] = bf2f((ushort)(u0.x >> 16));
                mzv[2] = bf2f((ushort)(u0.y & 0xffffu)); mzv[3] = bf2f((ushort)(u0.y >> 16));
                mzv[4] = bf2f((ushort)(u0.z & 0xffffu)); mzv[5] = bf2f((ushort)(u0.z >> 16));
                mzv[6] = bf2f((ushort)(u0.w & 0xffffu)); mzv[7] = bf2f((ushort)(u0.w >> 16));
                mzv[8] = bf2f((ushort)(u1.x & 0xffffu)); mzv[9] = bf2f((ushort)(u1.x >> 16));
                mzv[10]= bf2f((ushort)(u1.y & 0xffffu)); mzv[11]= bf2f((ushort)(u1.y >> 16));
                #pragma unroll
                for (int q = 0; q < 4; ++q) {
                    float dot = 0.f;
                    #pragma unroll
                    for (int l = 0; l < 12; ++l) dot = fmaf(wz[q][l], mzv[l], dot);
                    float sim = dot * (1.f/12.f);
                    float rv  = fmaxf(sim, 0.f);
                    float rv2 = rv * rv;
                    const int r = rg*8 + rq*4 + q, k = m*64 + c;
                    *(ushort*)((char*)fl + SWZ(r, k)) = f2bf(rv2*rv2);
                }
            }
        }
    }

    // ---------------- GEMM1: [64 x 512] x [512 x 512], wave n-slice = 64 ----------------
    const ushort* ws1 = ws + W1S_OFF;
    bf16x8 bb1[2][4];
    #pragma unroll
    for (int d = 0; d < 2; ++d)                   // preload tk=0,1 before the barrier
        #pragma unroll
        for (int tn = 0; tn < 4; ++tn)
            bb1[d][tn] = *(const bf16x8*)(ws1 + (size_t)((w*4 + tn)*16 + d)*512 + lane*8);

    __syncthreads();

    f32x4 acc[4][4];
    #pragma unroll
    for (int mt = 0; mt < 4; ++mt)
        #pragma unroll
        for (int tn = 0; tn < 4; ++tn)
            acc[mt][tn] = (f32x4){0.f,0.f,0.f,0.f};

    #pragma unroll
    for (int tk = 0; tk < 16; ++tk) {
        bf16x8 a[4];
        #pragma unroll
        for (int mt = 0; mt < 4; ++mt)
            a[mt] = *(const bf16x8*)((char*)fl + SWZ(mt*16 + lo, tk*32 + hi*8));
        bf16x8 cur[4];
        #pragma unroll
        for (int tn = 0; tn < 4; ++tn) cur[tn] = bb1[tk & 1][tn];
        if (tk < 14) {
            #pragma unroll
            for (int tn = 0; tn < 4; ++tn)
                bb1[tk & 1][tn] = *(const bf16x8*)(ws1 + (size_t)((w*4 + tn)*16 + tk + 2)*512 + lane*8);
        }
        #pragma unroll
        for (int tn = 0; tn < 4; ++tn)
            #pragma unroll
            for (int mt = 0; mt < 4; ++mt)
                acc[mt][tn] = __builtin_amdgcn_mfma_f32_16x16x32_bf16(a[mt], cur[tn], acc[mt][tn], 0, 0, 0);
    }

    // ---------------- bias + exact gelu (in regs) ----------------
    {
        float b1v[4];
        #pragma unroll
        for (int tn = 0; tn < 4; ++tn) b1v[tn] = b1[n0 + tn*16 + lo];
        #pragma unroll
        for (int mt = 0; mt < 4; ++mt)
            #pragma unroll
            for (int tn = 0; tn < 4; ++tn)
                #pragma unroll
                for (int e = 0; e < 4; ++e) {
                    float v = acc[mt][tn][e] + b1v[tn];
                    acc[mt][tn][e] = 0.5f * v * (1.f + erff(v * 0.70710678118654752f));
                }
    }

    // ---------------- LayerNorm: partials -> stats -> normalize -> hn bf16 LDS ----------------
    #pragma unroll
    for (int mt = 0; mt < 4; ++mt)
        #pragma unroll
        for (int e = 0; e < 4; ++e) {
            float s1 = 0.f, s2 = 0.f;
            #pragma unroll
            for (int tn = 0; tn < 4; ++tn) {
                float g = acc[mt][tn][e];
                s1 += g; s2 = fmaf(g, g, s2);
            }
            #pragma unroll
            for (int o = 1; o < 16; o <<= 1) {
                s1 += __shfl_xor(s1, o);
                s2 += __shfl_xor(s2, o);
            }
            if (lo == 0) {
                int row = mt*16 + hi*4 + e;
                part[row][w][0] = s1;
                part[row][w][1] = s2;
            }
        }
    __syncthreads();
    if (t < 64) {
        float s1 = 0.f, s2 = 0.f;
        #pragma unroll
        for (int ww = 0; ww < 8; ++ww) { s1 += part[t][ww][0]; s2 += part[t][ww][1]; }
        float mu  = s1 * (1.f/512.f);
        float var = s2 * (1.f/512.f) - mu*mu;
        mu_s[t] = mu;
        rs_s[t] = rsqrtf(var + 1e-5f);
    }
    __syncthreads();
    {
        float gv[4], bv[4];
        #pragma unroll
        for (int tn = 0; tn < 4; ++tn) {
            gv[tn] = gamma[n0 + tn*16 + lo];
            bv[tn] = beta[n0 + tn*16 + lo];
        }
        #pragma unroll
        for (int mt = 0; mt < 4; ++mt)
            #pragma unroll
            for (int e = 0; e < 4; ++e) {
                int row = mt*16 + hi*4 + e;
                float mu = mu_s[row], rs = rs_s[row];
                #pragma unroll
                for (int tn = 0; tn < 4; ++tn) {
                    float hn = (acc[mt][tn][e] - mu) * rs * gv[tn] + bv[tn];
                    int col = n0 + tn*16 + lo;
                    *(ushort*)((char*)fl + SWZ(row, col)) = f2bf(hn);
                }
            }
    }

    // ---------------- GEMM2: [64 x 512] x [512 x 256], wave n-slice = 32 ----------------
    const ushort* ws2 = ws + W2S_OFF;
    bf16x8 bb2[2][2];
    #pragma unroll
    for (int d = 0; d < 2; ++d)                   // preload tk=0,1 before the barrier
        #pragma unroll
        for (int tn = 0; tn < 2; ++tn)
            bb2[d][tn] = *(const bf16x8*)(ws2 + (size_t)((w*2 + tn)*16 + d)*512 + lane*8);

    __syncthreads();

    f32x4 acc2[4][2];
    #pragma unroll
    for (int mt = 0; mt < 4; ++mt)
        #pragma unroll
        for (int tn = 0; tn < 2; ++tn)
            acc2[mt][tn] = (f32x4){0.f,0.f,0.f,0.f};

    #pragma unroll
    for (int tk = 0; tk < 16; ++tk) {
        bf16x8 a[4];
        #pragma unroll
        for (int mt = 0; mt < 4; ++mt)
            a[mt] = *(const bf16x8*)((char*)fl + SWZ(mt*16 + lo, tk*32 + hi*8));
        bf16x8 cur[2];
        #pragma unroll
        for (int tn = 0; tn < 2; ++tn) cur[tn] = bb2[tk & 1][tn];
        if (tk < 14) {
            #pragma unroll
            for (int tn = 0; tn < 2; ++tn)
                bb2[tk & 1][tn] = *(const bf16x8*)(ws2 + (size_t)((w*2 + tn)*16 + tk + 2)*512 + lane*8);
        }
        #pragma unroll
        for (int tn = 0; tn < 2; ++tn)
            #pragma unroll
            for (int mt = 0; mt < 4; ++mt)
                acc2[mt][tn] = __builtin_amdgcn_mfma_f32_16x16x32_bf16(a[mt], cur[tn], acc2[mt][tn], 0, 0, 0);
    }

    // ---------------- + b2 -> LDS fp32 tile -> full-line coalesced stores ----------------
    __syncthreads();                              // all GEMM2 LDS reads retired
    {
        float* fl32 = (float*)fl;                 // [64][256] fp32 = 64 KB
        const int n2 = w * 32;
        float b2v[2];
        #pragma unroll
        for (int tn = 0; tn < 2; ++tn) b2v[tn] = b2[n2 + tn*16 + lo];
        #pragma unroll
        for (int mt = 0; mt < 4; ++mt)
            #pragma unroll
            for (int tn = 0; tn < 2; ++tn) {
                int col = n2 + tn*16 + lo;
                #pragma unroll
                for (int e = 0; e < 4; ++e) {
                    int row = mt*16 + hi*4 + e;
                    fl32[row*256 + col] = acc2[mt][tn][e] + b2v[tn];
                }
            }
    }
    __syncthreads();
    {
        const float4* src = (const float4*)fl;    // [64][64] float4
        float4* dst = (float4*)out;
        const int row = t >> 3;                   // 0..63
        const int sg  = t & 7;                    // 0..7
        #pragma unroll
        for (int it = 0; it < 8; ++it) {
            float4 v = src[row*64 + sg + it*8];
            dst[(size_t)(g0 + row)*64 + sg + it*8] = v;
        }
    }
}

extern "C" void kernel_launch(void* const* d_in, const int* in_sizes, int n_in,
                              void* d_out, int out_size, void* d_ws, size_t ws_size,
                              hipStream_t stream) {
    const float* x      = (const float*)d_in[0];
    const float* motifs = (const float*)d_in[1];
    const float* W1     = (const float*)d_in[2];
    const float* b1     = (const float*)d_in[3];
    const float* gamma  = (const float*)d_in[4];
    const float* beta   = (const float*)d_in[5];
    const float* W2     = (const float*)d_in[6];
    const float* b2     = (const float*)d_in[7];
    float* out = (float*)d_out;
    ushort* ws = (ushort*)d_ws;

    prep_kernel<<<(393216 + 512 + 255) / 256, 256, 0, stream>>>(W1, W2, motifs, ws);
    fused_kernel<<<512, 512, 0, stream>>>(x, ws, b1, gamma, beta, b2, out);
}

// Round 6
// 101.933 us; speedup vs baseline: 1.1129x; 1.1129x over previous
//
#include <hip/hip_runtime.h>
#include <math.h>

typedef __attribute__((ext_vector_type(8))) short bf16x8;
typedef __attribute__((ext_vector_type(4))) float f32x4;

#define W1S_OFF 0
#define W2S_OFF 262144
#define MZ_OFF  393216          // motifs_z, [p=m*64+c][16] bf16 (12 used, 4 pad)

__device__ __forceinline__ ushort f2bf(float x){
    union{float f; unsigned u;} v; v.f = x;
    unsigned r = v.u + 0x7fffu + ((v.u >> 16) & 1u);
    return (ushort)(r >> 16);
}
__device__ __forceinline__ float bf2f(ushort u){
    union{unsigned i; float f;} v; v.i = ((unsigned)u) << 16; return v.f;
}

// Pack W1 (512x512) and W2 (512x256) into bf16 MFMA-B-fragment order.
// B-frag layout: ws[((tn_g*16 + tk)*64 + lane)*8 + j] = W[k][n],
//   k = tk*32 + (lane>>4)*8 + j,  n = tn_g*16 + (lane&15).
__global__ __launch_bounds__(256) void prep_kernel(
    const float* __restrict__ W1, const float* __restrict__ W2,
    const float* __restrict__ motifs, ushort* __restrict__ ws)
{
    int idx = blockIdx.x * 256 + threadIdx.x;
    if (idx < 262144) {                        // W1: idx = k*512 + n
        int k = idx >> 9, n = idx & 511;
        int tk = k >> 5, j = k & 7, hig = (k >> 3) & 3;
        int tn = n >> 4, lo = n & 15;
        int lane = hig * 16 + lo;
        ws[W1S_OFF + (((tn*16 + tk)*64 + lane)*8 + j)] = f2bf(W1[idx]);
    } else if (idx < 393216) {                 // W2: i = k*256 + n
        int i = idx - 262144;
        int k = i >> 8, n = i & 255;
        int tk = k >> 5, j = k & 7, hig = (k >> 3) & 3;
        int tn = n >> 4, lo = n & 15;
        int lane = hig * 16 + lo;
        ws[W2S_OFF + (((tn*16 + tk)*64 + lane)*8 + j)] = f2bf(W2[i]);
    } else if (idx < 393216 + 512) {
        int p = idx - 393216;                  // p = m*64 + c
        const float* mp = motifs + p*12;
        float v[12]; float sm = 0.f;
        #pragma unroll
        for (int l = 0; l < 12; ++l){ v[l] = mp[l]; sm += v[l]; }
        float mean = sm * (1.f/12.f), sq = 0.f;
        #pragma unroll
        for (int l = 0; l < 12; ++l){ float d = v[l]-mean; sq = fmaf(d,d,sq); }
        float inv = 1.f / (sqrtf(sq*(1.f/12.f)) + 1e-8f);
        #pragma unroll
        for (int l = 0; l < 12; ++l) ws[MZ_OFF + p*16 + l] = f2bf((v[l]-mean)*inv);
        #pragma unroll
        for (int l = 12; l < 16; ++l) ws[MZ_OFF + p*16 + l] = 0;
    }
}

// Swizzled byte offset into the [64][512] bf16 LDS tile (conflict-free b128 A-frag reads)
#define SWZ(r, k) (((((r) << 9) + (k)) << 1) ^ (((r) & 7) << 4))

__global__ __launch_bounds__(512, 4) void fused_kernel(
    const float* __restrict__ x, const ushort* __restrict__ ws,
    const float* __restrict__ b1, const float* __restrict__ gamma,
    const float* __restrict__ beta, const float* __restrict__ b2,
    float* __restrict__ out)
{
    __shared__ __align__(16) ushort fl[64*512];   // 64 KB: flat -> hn -> fp32 out tile
    __shared__ float part[64][8][2];              // per-wave LN partials
    __shared__ float mu_s[64];
    __shared__ float rs_s[64];

    const int t  = threadIdx.x;
    const int g0 = blockIdx.x * 64;               // global row base (row = bi*4096+s)

    const int w    = t >> 6;          // wave 0..7
    const int lane = t & 63;
    const int hi   = lane >> 4;
    const int lo   = lane & 15;
    const int n0   = w * 64;

    // ---------------- Phase A: per-row sliding window, low register pressure ----------------
    {
        const int c  = t & 63;
        const int rg = t >> 6;                    // rows rg*8 .. rg*8+7
        const ushort* mzw = ws + MZ_OFF;
        const int sb0 = (g0 & 4095) + rg*8;       // row-in-batch of first handled row
        const size_t xbase = (size_t)(g0 & ~4095) * 64 + c;

        float wv[12];
        #pragma unroll
        for (int l = 0; l < 12; ++l) {            // initial window (left-clamped)
            int sw = sb0 - 11 + l; sw = sw < 0 ? 0 : sw;
            wv[l] = x[xbase + (size_t)sw * 64];
        }
        #pragma unroll 1
        for (int i = 0; i < 8; ++i) {
            if (i) {                              // slide by one row
                #pragma unroll
                for (int l = 0; l < 11; ++l) wv[l] = wv[l+1];
                wv[11] = x[xbase + (size_t)(sb0 + i) * 64];
            }
            float sm = 0.f;
            #pragma unroll
            for (int l = 0; l < 12; ++l) sm += wv[l];
            float mean = sm * (1.f/12.f), sq = 0.f;
            #pragma unroll
            for (int l = 0; l < 12; ++l){ float d = wv[l]-mean; sq = fmaf(d,d,sq); }
            float inv = 1.f / (sqrtf(sq*(1.f/12.f)) + 1e-8f);
            float wz[12];
            #pragma unroll
            for (int l = 0; l < 12; ++l) wz[l] = (wv[l]-mean)*inv;
            const int r = rg*8 + i;
            #pragma unroll
            for (int m = 0; m < 8; ++m) {
                const ushort* mp = mzw + (m*64 + c)*16;
                uint4 u0 = *(const uint4*)mp;
                uint2 u1 = *(const uint2*)(mp + 8);
                float dot = 0.f;
                dot = fmaf(wz[0],  bf2f((ushort)(u0.x & 0xffffu)), dot);
                dot = fmaf(wz[1],  bf2f((ushort)(u0.x >> 16)),     dot);
                dot = fmaf(wz[2],  bf2f((ushort)(u0.y & 0xffffu)), dot);
                dot = fmaf(wz[3],  bf2f((ushort)(u0.y >> 16)),     dot);
                dot = fmaf(wz[4],  bf2f((ushort)(u0.z & 0xffffu)), dot);
                dot = fmaf(wz[5],  bf2f((ushort)(u0.z >> 16)),     dot);
                dot = fmaf(wz[6],  bf2f((ushort)(u0.w & 0xffffu)), dot);
                dot = fmaf(wz[7],  bf2f((ushort)(u0.w >> 16)),     dot);
                dot = fmaf(wz[8],  bf2f((ushort)(u1.x & 0xffffu)), dot);
                dot = fmaf(wz[9],  bf2f((ushort)(u1.x >> 16)),     dot);
                dot = fmaf(wz[10], bf2f((ushort)(u1.y & 0xffffu)), dot);
                dot = fmaf(wz[11], bf2f((ushort)(u1.y >> 16)),     dot);
                float sim = dot * (1.f/12.f);
                float rv  = fmaxf(sim, 0.f);
                float rv2 = rv * rv;
                *(ushort*)((char*)fl + SWZ(r, m*64 + c)) = f2bf(rv2*rv2);
            }
        }
    }

    // ---------------- GEMM1: [64x512]x[512x512], 2-buffer prefetch, no copies ----------------
    const ushort* ws1 = ws + W1S_OFF;
    bf16x8 p0[4], p1[4];
    #pragma unroll
    for (int tn = 0; tn < 4; ++tn) {
        p0[tn] = *(const bf16x8*)(ws1 + (size_t)((w*4 + tn)*16 + 0)*512 + lane*8);
        p1[tn] = *(const bf16x8*)(ws1 + (size_t)((w*4 + tn)*16 + 1)*512 + lane*8);
    }

    __syncthreads();

    f32x4 acc[4][4];
    #pragma unroll
    for (int mt = 0; mt < 4; ++mt)
        #pragma unroll
        for (int tn = 0; tn < 4; ++tn)
            acc[mt][tn] = (f32x4){0.f,0.f,0.f,0.f};

    #pragma unroll
    for (int th = 0; th < 8; ++th) {
        {
            const int tk = 2*th;
            bf16x8 a0[4];
            #pragma unroll
            for (int mt = 0; mt < 4; ++mt)
                a0[mt] = *(const bf16x8*)((char*)fl + SWZ(mt*16 + lo, tk*32 + hi*8));
            #pragma unroll
            for (int tn = 0; tn < 4; ++tn)
                #pragma unroll
                for (int mt = 0; mt < 4; ++mt)
                    acc[mt][tn] = __builtin_amdgcn_mfma_f32_16x16x32_bf16(a0[mt], p0[tn], acc[mt][tn], 0, 0, 0);
            if (th < 7) {
                #pragma unroll
                for (int tn = 0; tn < 4; ++tn)
                    p0[tn] = *(const bf16x8*)(ws1 + (size_t)((w*4 + tn)*16 + tk + 2)*512 + lane*8);
            }
        }
        {
            const int tk = 2*th + 1;
            bf16x8 a1[4];
            #pragma unroll
            for (int mt = 0; mt < 4; ++mt)
                a1[mt] = *(const bf16x8*)((char*)fl + SWZ(mt*16 + lo, tk*32 + hi*8));
            #pragma unroll
            for (int tn = 0; tn < 4; ++tn)
                #pragma unroll
                for (int mt = 0; mt < 4; ++mt)
                    acc[mt][tn] = __builtin_amdgcn_mfma_f32_16x16x32_bf16(a1[mt], p1[tn], acc[mt][tn], 0, 0, 0);
            if (th < 7) {
                #pragma unroll
                for (int tn = 0; tn < 4; ++tn)
                    p1[tn] = *(const bf16x8*)(ws1 + (size_t)((w*4 + tn)*16 + tk + 2)*512 + lane*8);
            }
        }
    }

    // ---------------- bias + exact gelu (in regs) ----------------
    {
        float b1v[4];
        #pragma unroll
        for (int tn = 0; tn < 4; ++tn) b1v[tn] = b1[n0 + tn*16 + lo];
        #pragma unroll
        for (int mt = 0; mt < 4; ++mt)
            #pragma unroll
            for (int tn = 0; tn < 4; ++tn)
                #pragma unroll
                for (int e = 0; e < 4; ++e) {
                    float v = acc[mt][tn][e] + b1v[tn];
                    acc[mt][tn][e] = 0.5f * v * (1.f + erff(v * 0.70710678118654752f));
                }
    }

    // ---------------- LayerNorm: partials -> stats -> normalize -> hn bf16 LDS ----------------
    #pragma unroll
    for (int mt = 0; mt < 4; ++mt)
        #pragma unroll
        for (int e = 0; e < 4; ++e) {
            float s1 = 0.f, s2 = 0.f;
            #pragma unroll
            for (int tn = 0; tn < 4; ++tn) {
                float g = acc[mt][tn][e];
                s1 += g; s2 = fmaf(g, g, s2);
            }
            #pragma unroll
            for (int o = 1; o < 16; o <<= 1) {
                s1 += __shfl_xor(s1, o);
                s2 += __shfl_xor(s2, o);
            }
            if (lo == 0) {
                int row = mt*16 + hi*4 + e;
                part[row][w][0] = s1;
                part[row][w][1] = s2;
            }
        }
    __syncthreads();
    if (t < 64) {
        float s1 = 0.f, s2 = 0.f;
        #pragma unroll
        for (int ww = 0; ww < 8; ++ww) { s1 += part[t][ww][0]; s2 += part[t][ww][1]; }
        float mu  = s1 * (1.f/512.f);
        float var = s2 * (1.f/512.f) - mu*mu;
        mu_s[t] = mu;
        rs_s[t] = rsqrtf(var + 1e-5f);
    }
    __syncthreads();
    {
        float gv[4], bv[4];
        #pragma unroll
        for (int tn = 0; tn < 4; ++tn) {
            gv[tn] = gamma[n0 + tn*16 + lo];
            bv[tn] = beta[n0 + tn*16 + lo];
        }
        #pragma unroll
        for (int mt = 0; mt < 4; ++mt)
            #pragma unroll
            for (int e = 0; e < 4; ++e) {
                int row = mt*16 + hi*4 + e;
                float mu = mu_s[row], rs = rs_s[row];
                #pragma unroll
                for (int tn = 0; tn < 4; ++tn) {
                    float hn = (acc[mt][tn][e] - mu) * rs * gv[tn] + bv[tn];
                    int col = n0 + tn*16 + lo;
                    *(ushort*)((char*)fl + SWZ(row, col)) = f2bf(hn);
                }
            }
    }

    // ---------------- GEMM2: [64x512]x[512x256], 2-buffer prefetch ----------------
    const ushort* ws2 = ws + W2S_OFF;
    bf16x8 q0[2], q1[2];
    #pragma unroll
    for (int tn = 0; tn < 2; ++tn) {
        q0[tn] = *(const bf16x8*)(ws2 + (size_t)((w*2 + tn)*16 + 0)*512 + lane*8);
        q1[tn] = *(const bf16x8*)(ws2 + (size_t)((w*2 + tn)*16 + 1)*512 + lane*8);
    }

    __syncthreads();

    f32x4 acc2[4][2];
    #pragma unroll
    for (int mt = 0; mt < 4; ++mt)
        #pragma unroll
        for (int tn = 0; tn < 2; ++tn)
            acc2[mt][tn] = (f32x4){0.f,0.f,0.f,0.f};

    #pragma unroll
    for (int th = 0; th < 8; ++th) {
        {
            const int tk = 2*th;
            bf16x8 a0[4];
            #pragma unroll
            for (int mt = 0; mt < 4; ++mt)
                a0[mt] = *(const bf16x8*)((char*)fl + SWZ(mt*16 + lo, tk*32 + hi*8));
            #pragma unroll
            for (int tn = 0; tn < 2; ++tn)
                #pragma unroll
                for (int mt = 0; mt < 4; ++mt)
                    acc2[mt][tn] = __builtin_amdgcn_mfma_f32_16x16x32_bf16(a0[mt], q0[tn], acc2[mt][tn], 0, 0, 0);
            if (th < 7) {
                #pragma unroll
                for (int tn = 0; tn < 2; ++tn)
                    q0[tn] = *(const bf16x8*)(ws2 + (size_t)((w*2 + tn)*16 + tk + 2)*512 + lane*8);
            }
        }
        {
            const int tk = 2*th + 1;
            bf16x8 a1[4];
            #pragma unroll
            for (int mt = 0; mt < 4; ++mt)
                a1[mt] = *(const bf16x8*)((char*)fl + SWZ(mt*16 + lo, tk*32 + hi*8));
            #pragma unroll
            for (int tn = 0; tn < 2; ++tn)
                #pragma unroll
                for (int mt = 0; mt < 4; ++mt)
                    acc2[mt][tn] = __builtin_amdgcn_mfma_f32_16x16x32_bf16(a1[mt], q1[tn], acc2[mt][tn], 0, 0, 0);
            if (th < 7) {
                #pragma unroll
                for (int tn = 0; tn < 2; ++tn)
                    q1[tn] = *(const bf16x8*)(ws2 + (size_t)((w*2 + tn)*16 + tk + 2)*512 + lane*8);
            }
        }
    }

    // ---------------- + b2 -> swizzled fp32 LDS tile -> full-line stores ----------------
    __syncthreads();                              // all GEMM2 LDS reads retired
    {
        float* fl32 = (float*)fl;                 // [64][256] fp32, col4-XOR swizzled
        const int n2 = w * 32;
        float b2v[2];
        #pragma unroll
        for (int tn = 0; tn < 2; ++tn) b2v[tn] = b2[n2 + tn*16 + lo];
        #pragma unroll
        for (int mt = 0; mt < 4; ++mt)
            #pragma unroll
            for (int tn = 0; tn < 2; ++tn) {
                int col = n2 + tn*16 + lo;
                int c4 = col >> 2, ce = col & 3;
                #pragma unroll
                for (int e = 0; e < 4; ++e) {
                    int row = mt*16 + hi*4 + e;
                    fl32[row*256 + (((c4 ^ (row & 7)) << 2) | ce)] = acc2[mt][tn][e] + b2v[tn];
                }
            }
    }
    __syncthreads();
    {
        const float* fl32 = (const float*)fl;
        float4* dst = (float4*)out;
        const int row = t >> 3;                   // 0..63
        const int sg  = t & 7;                    // 0..7
        #pragma unroll
        for (int it = 0; it < 8; ++it) {
            int c4 = sg + it*8;
            float4 v = *(const float4*)&fl32[row*256 + ((c4 ^ (row & 7)) << 2)];
            dst[(size_t)(g0 + row)*64 + c4] = v;
        }
    }
}

extern "C" void kernel_launch(void* const* d_in, const int* in_sizes, int n_in,
                              void* d_out, int out_size, void* d_ws, size_t ws_size,
                              hipStream_t stream) {
    const float* x      = (const float*)d_in[0];
    const float* motifs = (const float*)d_in[1];
    const float* W1     = (const float*)d_in[2];
    const float* b1     = (const float*)d_in[3];
    const float* gamma  = (const float*)d_in[4];
    const float* beta   = (const float*)d_in[5];
    const float* W2     = (const float*)d_in[6];
    const float* b2     = (const float*)d_in[7];
    float* out = (float*)d_out;
    ushort* ws = (ushort*)d_ws;

    prep_kernel<<<(393216 + 512 + 255) / 256, 256, 0, stream>>>(W1, W2, motifs, ws);
    fused_kernel<<<512, 512, 0, stream>>>(x, ws, b1, gamma, beta, b2, out);
}

// Round 7
// 66.116 us; speedup vs baseline: 1.7158x; 1.5417x over previous
//
#include <hip/hip_runtime.h>
#include <math.h>

typedef __attribute__((ext_vector_type(8))) short bf16x8;
typedef __attribute__((ext_vector_type(4))) float f32x4;

#define W1S_OFF 0
#define W2S_OFF 262144
#define MZ_OFF  393216          // motifs_z, [p=m*64+c][16] bf16 (12 used, 4 pad)

__device__ __forceinline__ ushort f2bf(float x){
    union{float f; unsigned u;} v; v.f = x;
    unsigned r = v.u + 0x7fffu + ((v.u >> 16) & 1u);
    return (ushort)(r >> 16);
}
__device__ __forceinline__ float bf2f(ushort u){
    union{unsigned i; float f;} v; v.i = ((unsigned)u) << 16; return v.f;
}

// Pack W1 (512x512) and W2 (512x256) into bf16 MFMA-B-fragment order.
// B-frag layout: ws[((tn_g*16 + tk)*64 + lane)*8 + j] = W[k][n],
//   k = tk*32 + (lane>>4)*8 + j,  n = tn_g*16 + (lane&15).
__global__ __launch_bounds__(256) void prep_kernel(
    const float* __restrict__ W1, const float* __restrict__ W2,
    const float* __restrict__ motifs, ushort* __restrict__ ws)
{
    int idx = blockIdx.x * 256 + threadIdx.x;
    if (idx < 262144) {                        // W1: idx = k*512 + n
        int k = idx >> 9, n = idx & 511;
        int tk = k >> 5, j = k & 7, hig = (k >> 3) & 3;
        int tn = n >> 4, lo = n & 15;
        int lane = hig * 16 + lo;
        ws[W1S_OFF + (((tn*16 + tk)*64 + lane)*8 + j)] = f2bf(W1[idx]);
    } else if (idx < 393216) {                 // W2: i = k*256 + n
        int i = idx - 262144;
        int k = i >> 8, n = i & 255;
        int tk = k >> 5, j = k & 7, hig = (k >> 3) & 3;
        int tn = n >> 4, lo = n & 15;
        int lane = hig * 16 + lo;
        ws[W2S_OFF + (((tn*16 + tk)*64 + lane)*8 + j)] = f2bf(W2[i]);
    } else if (idx < 393216 + 512) {
        int p = idx - 393216;                  // p = m*64 + c
        const float* mp = motifs + p*12;
        float v[12]; float sm = 0.f;
        #pragma unroll
        for (int l = 0; l < 12; ++l){ v[l] = mp[l]; sm += v[l]; }
        float mean = sm * (1.f/12.f), sq = 0.f;
        #pragma unroll
        for (int l = 0; l < 12; ++l){ float d = v[l]-mean; sq = fmaf(d,d,sq); }
        float inv = 1.f / (sqrtf(sq*(1.f/12.f)) + 1e-8f);
        #pragma unroll
        for (int l = 0; l < 12; ++l) ws[MZ_OFF + p*16 + l] = f2bf((v[l]-mean)*inv);
        #pragma unroll
        for (int l = 12; l < 16; ++l) ws[MZ_OFF + p*16 + l] = 0;
    }
}

// Swizzled byte offset into the [32][512] bf16 LDS tile (conflict-free b128 A-frag reads)
#define SWZ(r, k) (((((r) << 9) + (k)) << 1) ^ (((r) & 7) << 4))

// One block = 32 rows, 512 threads (8 waves). acc[2][4]=32 regs -> no spill at 128-reg cap.
__global__ __launch_bounds__(512, 4) void fused_kernel(
    const float* __restrict__ x, const ushort* __restrict__ ws,
    const float* __restrict__ b1, const float* __restrict__ gamma,
    const float* __restrict__ beta, const float* __restrict__ b2,
    float* __restrict__ out)
{
    __shared__ __align__(16) ushort fl[32*512];   // 32 KB: flat -> hn -> fp32 out tile
    __shared__ float part[32][8][2];              // per-wave LN partials
    __shared__ float mu_s[32];
    __shared__ float rs_s[32];

    const int t  = threadIdx.x;
    const int g0 = blockIdx.x * 32;               // global row base (row = bi*4096+s)

    const int w    = t >> 6;          // wave 0..7
    const int lane = t & 63;
    const int hi   = lane >> 4;
    const int lo   = lane & 15;
    const int n0   = w * 64;

    // ---------------- Phase A: per-row window z-norm + motif dots -> flat bf16 ----------------
    {
        const int c  = t & 63;
        const int rg = t >> 6;                    // rows rg*4 .. rg*4+3
        const ushort* mzw = ws + MZ_OFF;
        const int sb0 = (g0 & 4095) + rg*4;       // row-in-batch of first handled row
        const size_t xbase = (size_t)(g0 & ~4095) * 64 + c;

        #pragma unroll 1
        for (int i = 0; i < 4; ++i) {
            const int sb = sb0 + i;
            float wv[12];
            #pragma unroll
            for (int l = 0; l < 12; ++l) {
                int sw = sb - 11 + l; sw = sw < 0 ? 0 : sw;
                wv[l] = x[xbase + (size_t)sw * 64];
            }
            float sm = 0.f;
            #pragma unroll
            for (int l = 0; l < 12; ++l) sm += wv[l];
            float mean = sm * (1.f/12.f), sq = 0.f;
            #pragma unroll
            for (int l = 0; l < 12; ++l){ float d = wv[l]-mean; sq = fmaf(d,d,sq); }
            float inv = 1.f / (sqrtf(sq*(1.f/12.f)) + 1e-8f);
            #pragma unroll
            for (int l = 0; l < 12; ++l) wv[l] = (wv[l]-mean)*inv;
            const int r = rg*4 + i;
            #pragma unroll
            for (int m = 0; m < 8; ++m) {
                const ushort* mp = mzw + (m*64 + c)*16;
                uint4 u0 = *(const uint4*)mp;
                uint2 u1 = *(const uint2*)(mp + 8);
                float dot = 0.f;
                dot = fmaf(wv[0],  bf2f((ushort)(u0.x & 0xffffu)), dot);
                dot = fmaf(wv[1],  bf2f((ushort)(u0.x >> 16)),     dot);
                dot = fmaf(wv[2],  bf2f((ushort)(u0.y & 0xffffu)), dot);
                dot = fmaf(wv[3],  bf2f((ushort)(u0.y >> 16)),     dot);
                dot = fmaf(wv[4],  bf2f((ushort)(u0.z & 0xffffu)), dot);
                dot = fmaf(wv[5],  bf2f((ushort)(u0.z >> 16)),     dot);
                dot = fmaf(wv[6],  bf2f((ushort)(u0.w & 0xffffu)), dot);
                dot = fmaf(wv[7],  bf2f((ushort)(u0.w >> 16)),     dot);
                dot = fmaf(wv[8],  bf2f((ushort)(u1.x & 0xffffu)), dot);
                dot = fmaf(wv[9],  bf2f((ushort)(u1.x >> 16)),     dot);
                dot = fmaf(wv[10], bf2f((ushort)(u1.y & 0xffffu)), dot);
                dot = fmaf(wv[11], bf2f((ushort)(u1.y >> 16)),     dot);
                float sim = dot * (1.f/12.f);
                float rv  = fmaxf(sim, 0.f);
                float rv2 = rv * rv;
                *(ushort*)((char*)fl + SWZ(r, m*64 + c)) = f2bf(rv2*rv2);
            }
        }
    }

    // ---------------- GEMM1: [32x512]x[512x512], 2-named-buffer prefetch ----------------
    const ushort* ws1 = ws + W1S_OFF;
    bf16x8 p0[4], p1[4];
    #pragma unroll
    for (int tn = 0; tn < 4; ++tn) {
        p0[tn] = *(const bf16x8*)(ws1 + (size_t)((w*4 + tn)*16 + 0)*512 + lane*8);
        p1[tn] = *(const bf16x8*)(ws1 + (size_t)((w*4 + tn)*16 + 1)*512 + lane*8);
    }

    __syncthreads();

    f32x4 acc[2][4];
    #pragma unroll
    for (int mt = 0; mt < 2; ++mt)
        #pragma unroll
        for (int tn = 0; tn < 4; ++tn)
            acc[mt][tn] = (f32x4){0.f,0.f,0.f,0.f};

    #pragma unroll
    for (int th = 0; th < 8; ++th) {
        {
            const int tk = 2*th;
            bf16x8 a0[2];
            #pragma unroll
            for (int mt = 0; mt < 2; ++mt)
                a0[mt] = *(const bf16x8*)((char*)fl + SWZ(mt*16 + lo, tk*32 + hi*8));
            #pragma unroll
            for (int tn = 0; tn < 4; ++tn)
                #pragma unroll
                for (int mt = 0; mt < 2; ++mt)
                    acc[mt][tn] = __builtin_amdgcn_mfma_f32_16x16x32_bf16(a0[mt], p0[tn], acc[mt][tn], 0, 0, 0);
            if (th < 7) {
                #pragma unroll
                for (int tn = 0; tn < 4; ++tn)
                    p0[tn] = *(const bf16x8*)(ws1 + (size_t)((w*4 + tn)*16 + tk + 2)*512 + lane*8);
            }
        }
        {
            const int tk = 2*th + 1;
            bf16x8 a1[2];
            #pragma unroll
            for (int mt = 0; mt < 2; ++mt)
                a1[mt] = *(const bf16x8*)((char*)fl + SWZ(mt*16 + lo, tk*32 + hi*8));
            #pragma unroll
            for (int tn = 0; tn < 4; ++tn)
                #pragma unroll
                for (int mt = 0; mt < 2; ++mt)
                    acc[mt][tn] = __builtin_amdgcn_mfma_f32_16x16x32_bf16(a1[mt], p1[tn], acc[mt][tn], 0, 0, 0);
            if (th < 7) {
                #pragma unroll
                for (int tn = 0; tn < 4; ++tn)
                    p1[tn] = *(const bf16x8*)(ws1 + (size_t)((w*4 + tn)*16 + tk + 2)*512 + lane*8);
            }
        }
    }

    // ---------------- bias + exact gelu (in regs) ----------------
    {
        float b1v[4];
        #pragma unroll
        for (int tn = 0; tn < 4; ++tn) b1v[tn] = b1[n0 + tn*16 + lo];
        #pragma unroll
        for (int mt = 0; mt < 2; ++mt)
            #pragma unroll
            for (int tn = 0; tn < 4; ++tn)
                #pragma unroll
                for (int e = 0; e < 4; ++e) {
                    float v = acc[mt][tn][e] + b1v[tn];
                    acc[mt][tn][e] = 0.5f * v * (1.f + erff(v * 0.70710678118654752f));
                }
    }

    // ---------------- LayerNorm: partials -> stats -> normalize -> hn bf16 LDS ----------------
    #pragma unroll
    for (int mt = 0; mt < 2; ++mt)
        #pragma unroll
        for (int e = 0; e < 4; ++e) {
            float s1 = 0.f, s2 = 0.f;
            #pragma unroll
            for (int tn = 0; tn < 4; ++tn) {
                float g = acc[mt][tn][e];
                s1 += g; s2 = fmaf(g, g, s2);
            }
            #pragma unroll
            for (int o = 1; o < 16; o <<= 1) {
                s1 += __shfl_xor(s1, o);
                s2 += __shfl_xor(s2, o);
            }
            if (lo == 0) {
                int row = mt*16 + hi*4 + e;
                part[row][w][0] = s1;
                part[row][w][1] = s2;
            }
        }
    __syncthreads();
    if (t < 32) {
        float s1 = 0.f, s2 = 0.f;
        #pragma unroll
        for (int ww = 0; ww < 8; ++ww) { s1 += part[t][ww][0]; s2 += part[t][ww][1]; }
        float mu  = s1 * (1.f/512.f);
        float var = s2 * (1.f/512.f) - mu*mu;
        mu_s[t] = mu;
        rs_s[t] = rsqrtf(var + 1e-5f);
    }
    __syncthreads();
    {
        float gv[4], bv[4];
        #pragma unroll
        for (int tn = 0; tn < 4; ++tn) {
            gv[tn] = gamma[n0 + tn*16 + lo];
            bv[tn] = beta[n0 + tn*16 + lo];
        }
        #pragma unroll
        for (int mt = 0; mt < 2; ++mt)
            #pragma unroll
            for (int e = 0; e < 4; ++e) {
                int row = mt*16 + hi*4 + e;
                float mu = mu_s[row], rs = rs_s[row];
                #pragma unroll
                for (int tn = 0; tn < 4; ++tn) {
                    float hn = (acc[mt][tn][e] - mu) * rs * gv[tn] + bv[tn];
                    int col = n0 + tn*16 + lo;
                    *(ushort*)((char*)fl + SWZ(row, col)) = f2bf(hn);
                }
            }
    }

    // ---------------- GEMM2: [32x512]x[512x256], 2-named-buffer prefetch ----------------
    const ushort* ws2 = ws + W2S_OFF;
    bf16x8 q0[2], q1[2];
    #pragma unroll
    for (int tn = 0; tn < 2; ++tn) {
        q0[tn] = *(const bf16x8*)(ws2 + (size_t)((w*2 + tn)*16 + 0)*512 + lane*8);
        q1[tn] = *(const bf16x8*)(ws2 + (size_t)((w*2 + tn)*16 + 1)*512 + lane*8);
    }

    __syncthreads();

    f32x4 acc2[2][2];
    #pragma unroll
    for (int mt = 0; mt < 2; ++mt)
        #pragma unroll
        for (int tn = 0; tn < 2; ++tn)
            acc2[mt][tn] = (f32x4){0.f,0.f,0.f,0.f};

    #pragma unroll
    for (int th = 0; th < 8; ++th) {
        {
            const int tk = 2*th;
            bf16x8 a0[2];
            #pragma unroll
            for (int mt = 0; mt < 2; ++mt)
                a0[mt] = *(const bf16x8*)((char*)fl + SWZ(mt*16 + lo, tk*32 + hi*8));
            #pragma unroll
            for (int tn = 0; tn < 2; ++tn)
                #pragma unroll
                for (int mt = 0; mt < 2; ++mt)
                    acc2[mt][tn] = __builtin_amdgcn_mfma_f32_16x16x32_bf16(a0[mt], q0[tn], acc2[mt][tn], 0, 0, 0);
            if (th < 7) {
                #pragma unroll
                for (int tn = 0; tn < 2; ++tn)
                    q0[tn] = *(const bf16x8*)(ws2 + (size_t)((w*2 + tn)*16 + tk + 2)*512 + lane*8);
            }
        }
        {
            const int tk = 2*th + 1;
            bf16x8 a1[2];
            #pragma unroll
            for (int mt = 0; mt < 2; ++mt)
                a1[mt] = *(const bf16x8*)((char*)fl + SWZ(mt*16 + lo, tk*32 + hi*8));
            #pragma unroll
            for (int tn = 0; tn < 2; ++tn)
                #pragma unroll
                for (int mt = 0; mt < 2; ++mt)
                    acc2[mt][tn] = __builtin_amdgcn_mfma_f32_16x16x32_bf16(a1[mt], q1[tn], acc2[mt][tn], 0, 0, 0);
            if (th < 7) {
                #pragma unroll
                for (int tn = 0; tn < 2; ++tn)
                    q1[tn] = *(const bf16x8*)(ws2 + (size_t)((w*2 + tn)*16 + tk + 2)*512 + lane*8);
            }
        }
    }

    // ---------------- + b2 -> swizzled fp32 LDS tile -> full-line stores ----------------
    __syncthreads();                              // all GEMM2 LDS reads retired
    {
        float* fl32 = (float*)fl;                 // [32][256] fp32, col4-XOR swizzled
        const int n2 = w * 32;
        float b2v[2];
        #pragma unroll
        for (int tn = 0; tn < 2; ++tn) b2v[tn] = b2[n2 + tn*16 + lo];
        #pragma unroll
        for (int mt = 0; mt < 2; ++mt)
            #pragma unroll
            for (int tn = 0; tn < 2; ++tn) {
                int col = n2 + tn*16 + lo;
                int c4 = col >> 2, ce = col & 3;
                #pragma unroll
                for (int e = 0; e < 4; ++e) {
                    int row = mt*16 + hi*4 + e;
                    fl32[row*256 + (((c4 ^ (row & 7)) << 2) | ce)] = acc2[mt][tn][e] + b2v[tn];
                }
            }
    }
    __syncthreads();
    {
        const float* fl32 = (const float*)fl;
        float4* dst = (float4*)out;
        const int row = t >> 4;                   // 0..31
        const int sg  = t & 15;                   // 0..15
        #pragma unroll
        for (int it = 0; it < 4; ++it) {
            int c4 = sg + it*16;
            float4 v = *(const float4*)&fl32[row*256 + ((c4 ^ (row & 7)) << 2)];
            dst[(size_t)(g0 + row)*64 + c4] = v;
        }
    }
}

extern "C" void kernel_launch(void* const* d_in, const int* in_sizes, int n_in,
                              void* d_out, int out_size, void* d_ws, size_t ws_size,
                              hipStream_t stream) {
    const float* x      = (const float*)d_in[0];
    const float* motifs = (const float*)d_in[1];
    const float* W1     = (const float*)d_in[2];
    const float* b1     = (const float*)d_in[3];
    const float* gamma  = (const float*)d_in[4];
    const float* beta   = (const float*)d_in[5];
    const float* W2     = (const float*)d_in[6];
    const float* b2     = (const float*)d_in[7];
    float* out = (float*)d_out;
    ushort* ws = (ushort*)d_ws;

    prep_kernel<<<(393216 + 512 + 255) / 256, 256, 0, stream>>>(W1, W2, motifs, ws);
    fused_kernel<<<1024, 512, 0, stream>>>(x, ws, b1, gamma, beta, b2, out);
}